// Round 7
// baseline (221.309 us; speedup 1.0000x reference)
//
#include <hip/hip_runtime.h>
#include <hip/hip_bf16.h>

// Fused MHA: B=2, L=2048, E=1024, H=16, Dh=64. fp32 in/out, bf16 MFMA compute.
// Stage 0: one fused fp32->bf16 convert kernel (6 tensors).
// Stage 1: projection GEMM -> Q (pre-scaled by log2e/8, (b,h,l,d)), K (b,h,l,d), V^T (b,h,d,l).
//          XOR-swizzled staging/reads (R6).
// Stage 2: flash attention, S^T formulation (K*Q^T), max-free streaming softmax.
//          R7: KV-sequence split x2 (blockIdx.z) -> 1024 blocks / 4096 waves (grid was the
//          8-waves/CU cap in R5/R6). Halves emit unnormalized O via atomicAdd into zeroed
//          d_out + psum partials to ws; norm_kernel divides at the end.

typedef __attribute__((ext_vector_type(8))) short short8;
typedef __attribute__((ext_vector_type(4))) short short4v;
typedef __attribute__((ext_vector_type(4))) float floatx4;

#define L_SEQ 2048
#define EMB 1024
#define NH 16
#define DH 64
#define QSCALE 0.18033688011112042f  // log2(e) / sqrt(64)

__device__ __forceinline__ void gl16(const void* g, void* l) {
  __builtin_amdgcn_global_load_lds(
      (const __attribute__((address_space(1))) void*)g,
      (__attribute__((address_space(3))) void*)l, 16, 0, 0);
}

// ---------------- fused fp32 -> bf16 convert (6 tensors) ----------------
__global__ void cvt6_kernel(const float* __restrict__ s0, const float* __restrict__ s1,
                            const float* __restrict__ s2, const float* __restrict__ s3,
                            const float* __restrict__ s4, const float* __restrict__ s5,
                            __hip_bfloat16* __restrict__ d0, __hip_bfloat16* __restrict__ d1,
                            __hip_bfloat16* __restrict__ d2, __hip_bfloat16* __restrict__ d3,
                            __hip_bfloat16* __restrict__ d4, __hip_bfloat16* __restrict__ d5,
                            int nx8, int nw8) {
  const int t = blockIdx.y;
  const float* src = (t == 0) ? s0 : (t == 1) ? s1 : (t == 2) ? s2
                   : (t == 3) ? s3 : (t == 4) ? s4 : s5;
  __hip_bfloat16* dst = (t == 0) ? d0 : (t == 1) ? d1 : (t == 2) ? d2
                      : (t == 3) ? d3 : (t == 4) ? d4 : d5;
  const int n8 = (t < 3) ? nx8 : nw8;
  int i = blockIdx.x * blockDim.x + threadIdx.x;
  const int stride = gridDim.x * blockDim.x;
  for (; i < n8; i += stride) {
    const float4* s4p = (const float4*)src;
    float4 a = s4p[2 * i];
    float4 b = s4p[2 * i + 1];
    union { short8 v; __hip_bfloat16 h[8]; } u;
    u.h[0] = __float2bfloat16(a.x); u.h[1] = __float2bfloat16(a.y);
    u.h[2] = __float2bfloat16(a.z); u.h[3] = __float2bfloat16(a.w);
    u.h[4] = __float2bfloat16(b.x); u.h[5] = __float2bfloat16(b.y);
    u.h[6] = __float2bfloat16(b.z); u.h[7] = __float2bfloat16(b.w);
    *(short8*)(dst + 8 * i) = u.v;
  }
}

// ---------------- projection GEMM ----------------
// C[m,n] = sum_k X[m,k] * W[n,k] + bias[n];  m in [0,4096), n in [0,1024) per proj.
// grid = (32, 24): by/8 selects proj p, by%8 selects n-tile. 128x128 tile, BK=64.
// LDS tiles XOR-swizzled in 16B chunks: row r's logical chunk c lives at c ^ (r&7).
#define CPAD 136  // epilogue LDS row stride (elements): 272 B rotates banks, keeps 16B align
__global__ __launch_bounds__(256) void proj_kernel(
    const __hip_bfloat16* __restrict__ xq, const __hip_bfloat16* __restrict__ xk,
    const __hip_bfloat16* __restrict__ xv,
    const __hip_bfloat16* __restrict__ wqb, const __hip_bfloat16* __restrict__ wkb,
    const __hip_bfloat16* __restrict__ wvb,
    const float* __restrict__ bq, const float* __restrict__ bk,
    const float* __restrict__ bv,
    __hip_bfloat16* __restrict__ Qb, __hip_bfloat16* __restrict__ Kb,
    __hip_bfloat16* __restrict__ Vt) {
  __shared__ __align__(16) __hip_bfloat16 lds[128 * CPAD];  // staging uses [0,16384); epilogue all
  const int tid = threadIdx.x;
  const int bx = blockIdx.x;
  const int by = blockIdx.y;
  const int p = by >> 3;
  const int n0 = (by & 7) * 128;
  const int m0 = bx * 128;
  const __hip_bfloat16* X = (p == 0) ? xq : (p == 1) ? xk : xv;
  const __hip_bfloat16* W = (p == 0) ? wqb : (p == 1) ? wkb : wvb;
  const float* bias = (p == 0) ? bq : (p == 1) ? bk : bv;

  const int w = tid >> 6, ln = tid & 63;
  const int wm = w & 1, wn = w >> 1;
  const int quad = ln >> 4, lr = ln & 15;

  floatx4 acc[4][4];
#pragma unroll
  for (int i = 0; i < 4; ++i)
#pragma unroll
    for (int j = 0; j < 4; ++j) acc[i][j] = (floatx4){0.f, 0.f, 0.f, 0.f};

  const int srow = tid >> 3;                              // staging row within 32-row chunk
  const int scol = (((tid & 7) ^ ((tid >> 3) & 7)) * 8);  // swizzled source col

  for (int kt = 0; kt < 16; ++kt) {
    const int k0 = kt * 64;
#pragma unroll
    for (int i = 0; i < 4; ++i) {
      gl16(X + (size_t)(m0 + i * 32 + srow) * EMB + k0 + scol,
           lds + i * 2048 + tid * 8);
      gl16(W + (size_t)(n0 + i * 32 + srow) * EMB + k0 + scol,
           lds + 8192 + i * 2048 + tid * 8);
    }
    __syncthreads();
#pragma unroll
    for (int ks = 0; ks < 2; ++ks) {
      short8 af[4], bf[4];
#pragma unroll
      for (int mt = 0; mt < 4; ++mt)
        af[mt] = *(const short8*)(lds + (wm * 64 + mt * 16 + lr) * 64 +
                                  (((ks * 4 + quad) ^ (lr & 7)) * 8));
#pragma unroll
      for (int nt = 0; nt < 4; ++nt)
        bf[nt] = *(const short8*)(lds + 8192 + (wn * 64 + nt * 16 + lr) * 64 +
                                  (((ks * 4 + quad) ^ (lr & 7)) * 8));
#pragma unroll
      for (int mt = 0; mt < 4; ++mt)
#pragma unroll
        for (int nt = 0; nt < 4; ++nt)
          acc[mt][nt] = __builtin_amdgcn_mfma_f32_16x16x32_bf16(
              af[mt], bf[nt], acc[mt][nt], 0, 0, 0);
    }
    __syncthreads();
  }

  // ---- epilogue: C tile -> LDS -> coalesced global stores ----
  // C/D layout: col = lane&15, rows = quad*4 + r.
  if (p == 2) {
    // LDS holds transposed tile [n][m] so consecutive m (the 4 regs) pack to b64.
#pragma unroll
    for (int nt = 0; nt < 4; ++nt) {
      const int nl = wn * 64 + nt * 16 + lr;
      const float bb = bias[n0 + nl];
#pragma unroll
      for (int mt = 0; mt < 4; ++mt) {
        union { short4v v; __hip_bfloat16 h4[4]; } u;
#pragma unroll
        for (int r = 0; r < 4; ++r) u.h4[r] = __float2bfloat16(acc[mt][nt][r] + bb);
        *(short4v*)(&lds[nl * CPAD + wm * 64 + mt * 16 + quad * 4]) = u.v;
      }
    }
  } else {
    const float scl = (p == 0) ? QSCALE : 1.0f;
#pragma unroll
    for (int nt = 0; nt < 4; ++nt) {
      const int nl = wn * 64 + nt * 16 + lr;
      const float bb = bias[n0 + nl];
#pragma unroll
      for (int mt = 0; mt < 4; ++mt)
#pragma unroll
        for (int r = 0; r < 4; ++r)
          lds[(wm * 64 + mt * 16 + quad * 4 + r) * CPAD + nl] =
              __float2bfloat16((acc[mt][nt][r] + bb) * scl);
    }
  }
  __syncthreads();

  // cooperative store: thread t -> tile row (t>>1), half-row (t&1): 64 el = 128 B.
  {
    const int tr = tid >> 1, half = tid & 1;
    const int b = m0 >> 11;
    const __hip_bfloat16* src = lds + tr * CPAD + half * 64;
    __hip_bfloat16* g;
    if (p == 2) {
      const int ng = n0 + tr;
      const int h = ng >> 6, d = ng & 63;
      g = Vt + ((size_t)((b * NH + h) * DH + d)) * L_SEQ + (m0 & 2047) + half * 64;
    } else {
      __hip_bfloat16* dst = (p == 0) ? Qb : Kb;
      const int m = m0 + tr;
      const int h = (n0 >> 6) + half;
      g = dst + ((size_t)((b * NH + h) * L_SEQ + (m & 2047))) * DH;
    }
#pragma unroll
    for (int j = 0; j < 8; ++j)
      *(short8*)(g + j * 8) = *(const short8*)(src + j * 8);
  }
}

// ---------------- flash attention (S^T formulation, max-free softmax, s-split) ----
// grid = (16 q-tiles of 128, 32 bh, 2 s-halves). block = 256 (4 waves), q=32/wave.
// Each block handles 1024 keys (16 iters of 64, dbuf). Emits UNNORMALIZED O via
// atomicAdd into zeroed d_out (fp32 add commutative -> deterministic) and psum
// partials to psP[sh][bh][q]. K/V LDS XOR-swizzled; P swizzle with bit3-fold.
__global__ __launch_bounds__(256, 4) void attn_kernel(
    const __hip_bfloat16* __restrict__ Qb, const __hip_bfloat16* __restrict__ Kb,
    const __hip_bfloat16* __restrict__ Vt, float* __restrict__ out,
    float* __restrict__ psP) {
  __shared__ __align__(16) __hip_bfloat16 Kl[2][4096];   // [s][d] swizzled, 2 x 8 KB
  __shared__ __align__(16) __hip_bfloat16 Vl[2][4096];   // [d][s] swizzled, 2 x 8 KB
  __shared__ __align__(16) __hip_bfloat16 Pl[4][2048];   // per-wave P [q=32][s=64], 4 x 4 KB

  const int tid = threadIdx.x;
  const int w = tid >> 6, ln = tid & 63;
  const int quad = ln >> 4, lr = ln & 15;
  const int bh = blockIdx.y;
  const int sh = blockIdx.z;
  const int sbase = sh * 1024;
  const int q0 = blockIdx.x * 128 + w * 32;
  const __hip_bfloat16* Qp = Qb + (size_t)bh * L_SEQ * DH;
  const __hip_bfloat16* Kp = Kb + (size_t)bh * L_SEQ * DH;
  const __hip_bfloat16* Vp = Vt + (size_t)bh * DH * L_SEQ;

  // Q fragments as MFMA B-operand: B[n=q][k=d]; lane: n = lr, k = quad*8+j.
  short8 qf[2][2];
#pragma unroll
  for (int qs = 0; qs < 2; ++qs)
#pragma unroll
    for (int kk = 0; kk < 2; ++kk)
      qf[qs][kk] = *(const short8*)(Qp + (size_t)(q0 + qs * 16 + lr) * DH + kk * 32 + quad * 8);

  // staging: 512 16B-chunks per tile, 256 threads -> 2 chunks each per tile.
  int koff[2], voff[2], loff[2];
#pragma unroll
  for (int i = 0; i < 2; ++i) {
    const int idx = i * 256 + tid;
    const int srow = idx >> 3;
    const int c = (idx & 7) ^ (srow & 7);
    koff[i] = srow * DH + c * 8;      // K: [s][d]
    voff[i] = srow * L_SEQ + c * 8;   // V^T: [d][s]
    loff[i] = idx * 8;
  }

  floatx4 acc[2][4];  // [qs][nt], rows = q quad*4+r, col = d nt*16+lr
  float psum[2];
#pragma unroll
  for (int qs = 0; qs < 2; ++qs) {
    psum[qs] = 0.f;
#pragma unroll
    for (int nt = 0; nt < 4; ++nt) acc[qs][nt] = (floatx4){0.f, 0.f, 0.f, 0.f};
  }

  // prologue stage for iter 0
#pragma unroll
  for (int i = 0; i < 2; ++i) gl16(Kp + (size_t)sbase * DH + koff[i], &Kl[0][loff[i]]);
#pragma unroll
  for (int i = 0; i < 2; ++i) gl16(Vp + sbase + voff[i], &Vl[0][loff[i]]);

  const int xsw = lr & 7;                           // K/V swizzle (row&7 == lr&7)
  const int xswp = (lr & 7) ^ ((lr >> 3) << 2);     // P swizzle with bit3-fold

  for (int it = 0; it < 16; ++it) {
    __syncthreads();  // drains stage(it) issued one iteration ago
    if (it + 1 < 16) {
      const int s0 = sbase + (it + 1) * 64;
      const int bf = (it + 1) & 1;
#pragma unroll
      for (int i = 0; i < 2; ++i) gl16(Kp + (size_t)s0 * DH + koff[i], &Kl[bf][loff[i]]);
#pragma unroll
      for (int i = 0; i < 2; ++i) gl16(Vp + s0 + voff[i], &Vl[bf][loff[i]]);
    }
    const __hip_bfloat16* Kt = Kl[it & 1];
    const __hip_bfloat16* Vtile = Vl[it & 1];

    // S^T = K * Q^T, one 16-row s-subtile (mt) at a time; softmax + P write inline.
#pragma unroll
    for (int mt = 0; mt < 4; ++mt) {
      floatx4 sc[2];
#pragma unroll
      for (int qs = 0; qs < 2; ++qs) sc[qs] = (floatx4){0.f, 0.f, 0.f, 0.f};
#pragma unroll
      for (int kk = 0; kk < 2; ++kk) {
        const short8 kf = *(const short8*)(Kt + ((mt * 16 + lr) * 8 + ((kk * 4 + quad) ^ xsw)) * 8);
#pragma unroll
        for (int qs = 0; qs < 2; ++qs)
          sc[qs] = __builtin_amdgcn_mfma_f32_16x16x32_bf16(kf, qf[qs][kk], sc[qs], 0, 0, 0);
      }
      const int cch = mt * 2 + (quad >> 1);
#pragma unroll
      for (int qs = 0; qs < 2; ++qs) {
        union { short4v v; __hip_bfloat16 h4[4]; } u;
#pragma unroll
        for (int r = 0; r < 4; ++r) {
          const float pv = __builtin_amdgcn_exp2f(sc[qs][r]);
          psum[qs] += pv;
          u.h4[r] = __float2bfloat16(pv);
        }
        const int row = qs * 16 + lr;  // row&7==lr&7, row>>3&1==lr>>3
        *(short4v*)(&Pl[w][row * 64 + ((cch ^ xswp) * 8 + (quad & 1) * 4)]) = u.v;
      }
    }

    // O += P V  (A = P [q][s], B = V^T [d][s])
#pragma unroll
    for (int kk = 0; kk < 2; ++kk) {
      short8 vf[4];
#pragma unroll
      for (int nt = 0; nt < 4; ++nt)
        vf[nt] = *(const short8*)(Vtile + ((nt * 16 + lr) * 8 + ((kk * 4 + quad) ^ xsw)) * 8);
#pragma unroll
      for (int qs = 0; qs < 2; ++qs) {
        const short8 pf = *(const short8*)(&Pl[w][(qs * 16 + lr) * 64 + ((kk * 4 + quad) ^ xswp) * 8]);
#pragma unroll
        for (int nt = 0; nt < 4; ++nt)
          acc[qs][nt] = __builtin_amdgcn_mfma_f32_16x16x32_bf16(pf, vf[nt], acc[qs][nt], 0, 0, 0);
      }
    }
  }

  // psum: lane holds partial (its quad's s-slice) for q = qs*16 + lr; sum across quads.
#pragma unroll
  for (int qs = 0; qs < 2; ++qs) {
    psum[qs] += __shfl_xor(psum[qs], 16, 64);
    psum[qs] += __shfl_xor(psum[qs], 32, 64);
  }

  // psum partial store (16 lanes of quad 0 cover q = qs*16 + lr)
  if (quad == 0) {
#pragma unroll
    for (int qs = 0; qs < 2; ++qs)
      psP[sh * (32 * L_SEQ) + bh * L_SEQ + q0 + qs * 16 + lr] = psum[qs];
  }

  // unnormalized O accumulate (d_out pre-zeroed; fp32 atomicAdd is commutative)
  const int b = bh >> 4, h = bh & 15;
#pragma unroll
  for (int qs = 0; qs < 2; ++qs) {
#pragma unroll
    for (int r = 0; r < 4; ++r) {
      const int lq = q0 + qs * 16 + quad * 4 + r;
#pragma unroll
      for (int nt = 0; nt < 4; ++nt)
        atomicAdd(&out[((size_t)(b * L_SEQ + lq)) * EMB + h * DH + nt * 16 + lr],
                  acc[qs][nt][r]);
    }
  }
}

// ---------------- normalize: out /= (psum_half0 + psum_half1) ----------------
__global__ __launch_bounds__(256) void norm_kernel(float* __restrict__ out,
                                                   const float* __restrict__ psP) {
  const int idx4 = blockIdx.x * blockDim.x + threadIdx.x;  // one float4 each
  const int flat = idx4 * 4;
  const int e = flat & 1023;
  const int l = (flat >> 10) & 2047;
  const int b = flat >> 21;
  const int bh = b * NH + (e >> 6);
  const float ps = psP[bh * L_SEQ + l] + psP[32 * L_SEQ + bh * L_SEQ + l];
  const float inv = 1.0f / ps;
  float4 v = ((float4*)out)[idx4];
  v.x *= inv; v.y *= inv; v.z *= inv; v.w *= inv;
  ((float4*)out)[idx4] = v;
}

extern "C" void kernel_launch(void* const* d_in, const int* in_sizes, int n_in,
                              void* d_out, int out_size, void* d_ws, size_t ws_size,
                              hipStream_t stream) {
  const float* xq = (const float*)d_in[0];
  const float* xk = (const float*)d_in[1];
  const float* xv = (const float*)d_in[2];
  const float* wq = (const float*)d_in[3];
  const float* bq = (const float*)d_in[4];
  const float* wk = (const float*)d_in[5];
  const float* bk = (const float*)d_in[6];
  const float* wv = (const float*)d_in[7];
  const float* bv = (const float*)d_in[8];

  const size_t NX = (size_t)4096 * 1024;  // x / q / k / v elements
  const size_t NW = (size_t)1024 * 1024;  // weight elements
  __hip_bfloat16* xbq = (__hip_bfloat16*)d_ws;
  __hip_bfloat16* xbk = xbq + NX;
  __hip_bfloat16* xbv = xbk + NX;
  __hip_bfloat16* wbq = xbv + NX;
  __hip_bfloat16* wbk = wbq + NW;
  __hip_bfloat16* wbv = wbk + NW;
  __hip_bfloat16* Qb = wbv + NW;
  __hip_bfloat16* Kb = Qb + NX;
  __hip_bfloat16* Vt = Kb + NX;
  // psum partials [2][32][2048] fp32 = 512 KB, overlaid on xbv (dead after proj)
  float* psP = (float*)xbv;
  // total ws use: 56.6 MB

  hipMemsetAsync(d_out, 0, (size_t)out_size * sizeof(float), stream);

  cvt6_kernel<<<dim3(1024, 6), 256, 0, stream>>>(xq, xk, xv, wq, wk, wv,
                                                 xbq, xbk, xbv, wbq, wbk, wbv,
                                                 (int)(NX / 8), (int)(NW / 8));

  proj_kernel<<<dim3(32, 24), 256, 0, stream>>>(xbq, xbk, xbv, wbq, wbk, wbv,
                                                bq, bk, bv, Qb, Kb, Vt);
  attn_kernel<<<dim3(16, 32, 2), 256, 0, stream>>>(Qb, Kb, Vt, (float*)d_out, psP);
  norm_kernel<<<4096, 256, 0, stream>>>((float*)d_out, psP);
}

// Round 8
// 194.772 us; speedup vs baseline: 1.1362x; 1.1362x over previous
//
#include <hip/hip_runtime.h>
#include <hip/hip_bf16.h>

// Fused MHA: B=2, L=2048, E=1024, H=16, Dh=64. fp32 in/out, bf16 MFMA compute.
// Stage 0: one fused fp32->bf16 convert kernel (6 tensors).
// Stage 1: projection GEMM -> Q (pre-scaled by log2e/8, (b,h,l,d)), K (b,h,l,d), V^T (b,h,d,l).
//          XOR-swizzled staging/reads (R6).
// Stage 2: flash attention, S^T formulation, max-free streaming softmax.
//          R8: q=64/wave (halves per-q K/V LDS reads vs R6) + s-split x2 via blockIdx.z
//          (keeps 8 waves/CU), NO atomics: each half writes bf16 O-partials to dead ws
//          regions; norm_kernel sums halves and divides by psum. No d_out memset needed.

typedef __attribute__((ext_vector_type(8))) short short8;
typedef __attribute__((ext_vector_type(4))) short short4v;
typedef __attribute__((ext_vector_type(4))) float floatx4;

#define L_SEQ 2048
#define EMB 1024
#define NH 16
#define DH 64
#define QSCALE 0.18033688011112042f  // log2(e) / sqrt(64)

__device__ __forceinline__ void gl16(const void* g, void* l) {
  __builtin_amdgcn_global_load_lds(
      (const __attribute__((address_space(1))) void*)g,
      (__attribute__((address_space(3))) void*)l, 16, 0, 0);
}

// ---------------- fused fp32 -> bf16 convert (6 tensors) ----------------
__global__ void cvt6_kernel(const float* __restrict__ s0, const float* __restrict__ s1,
                            const float* __restrict__ s2, const float* __restrict__ s3,
                            const float* __restrict__ s4, const float* __restrict__ s5,
                            __hip_bfloat16* __restrict__ d0, __hip_bfloat16* __restrict__ d1,
                            __hip_bfloat16* __restrict__ d2, __hip_bfloat16* __restrict__ d3,
                            __hip_bfloat16* __restrict__ d4, __hip_bfloat16* __restrict__ d5,
                            int nx8, int nw8) {
  const int t = blockIdx.y;
  const float* src = (t == 0) ? s0 : (t == 1) ? s1 : (t == 2) ? s2
                   : (t == 3) ? s3 : (t == 4) ? s4 : s5;
  __hip_bfloat16* dst = (t == 0) ? d0 : (t == 1) ? d1 : (t == 2) ? d2
                      : (t == 3) ? d3 : (t == 4) ? d4 : d5;
  const int n8 = (t < 3) ? nx8 : nw8;
  int i = blockIdx.x * blockDim.x + threadIdx.x;
  const int stride = gridDim.x * blockDim.x;
  for (; i < n8; i += stride) {
    const float4* s4p = (const float4*)src;
    float4 a = s4p[2 * i];
    float4 b = s4p[2 * i + 1];
    union { short8 v; __hip_bfloat16 h[8]; } u;
    u.h[0] = __float2bfloat16(a.x); u.h[1] = __float2bfloat16(a.y);
    u.h[2] = __float2bfloat16(a.z); u.h[3] = __float2bfloat16(a.w);
    u.h[4] = __float2bfloat16(b.x); u.h[5] = __float2bfloat16(b.y);
    u.h[6] = __float2bfloat16(b.z); u.h[7] = __float2bfloat16(b.w);
    *(short8*)(dst + 8 * i) = u.v;
  }
}

// ---------------- projection GEMM ----------------
// C[m,n] = sum_k X[m,k] * W[n,k] + bias[n];  m in [0,4096), n in [0,1024) per proj.
// grid = (32, 24): by/8 selects proj p, by%8 selects n-tile. 128x128 tile, BK=64.
// LDS tiles XOR-swizzled in 16B chunks: row r's logical chunk c lives at c ^ (r&7).
#define CPAD 136  // epilogue LDS row stride (elements): 272 B rotates banks, keeps 16B align
__global__ __launch_bounds__(256) void proj_kernel(
    const __hip_bfloat16* __restrict__ xq, const __hip_bfloat16* __restrict__ xk,
    const __hip_bfloat16* __restrict__ xv,
    const __hip_bfloat16* __restrict__ wqb, const __hip_bfloat16* __restrict__ wkb,
    const __hip_bfloat16* __restrict__ wvb,
    const float* __restrict__ bq, const float* __restrict__ bk,
    const float* __restrict__ bv,
    __hip_bfloat16* __restrict__ Qb, __hip_bfloat16* __restrict__ Kb,
    __hip_bfloat16* __restrict__ Vt) {
  __shared__ __align__(16) __hip_bfloat16 lds[128 * CPAD];  // staging uses [0,16384); epilogue all
  const int tid = threadIdx.x;
  const int bx = blockIdx.x;
  const int by = blockIdx.y;
  const int p = by >> 3;
  const int n0 = (by & 7) * 128;
  const int m0 = bx * 128;
  const __hip_bfloat16* X = (p == 0) ? xq : (p == 1) ? xk : xv;
  const __hip_bfloat16* W = (p == 0) ? wqb : (p == 1) ? wkb : wvb;
  const float* bias = (p == 0) ? bq : (p == 1) ? bk : bv;

  const int w = tid >> 6, ln = tid & 63;
  const int wm = w & 1, wn = w >> 1;
  const int quad = ln >> 4, lr = ln & 15;

  floatx4 acc[4][4];
#pragma unroll
  for (int i = 0; i < 4; ++i)
#pragma unroll
    for (int j = 0; j < 4; ++j) acc[i][j] = (floatx4){0.f, 0.f, 0.f, 0.f};

  const int srow = tid >> 3;                              // staging row within 32-row chunk
  const int scol = (((tid & 7) ^ ((tid >> 3) & 7)) * 8);  // swizzled source col

  for (int kt = 0; kt < 16; ++kt) {
    const int k0 = kt * 64;
#pragma unroll
    for (int i = 0; i < 4; ++i) {
      gl16(X + (size_t)(m0 + i * 32 + srow) * EMB + k0 + scol,
           lds + i * 2048 + tid * 8);
      gl16(W + (size_t)(n0 + i * 32 + srow) * EMB + k0 + scol,
           lds + 8192 + i * 2048 + tid * 8);
    }
    __syncthreads();
#pragma unroll
    for (int ks = 0; ks < 2; ++ks) {
      short8 af[4], bf[4];
#pragma unroll
      for (int mt = 0; mt < 4; ++mt)
        af[mt] = *(const short8*)(lds + (wm * 64 + mt * 16 + lr) * 64 +
                                  (((ks * 4 + quad) ^ (lr & 7)) * 8));
#pragma unroll
      for (int nt = 0; nt < 4; ++nt)
        bf[nt] = *(const short8*)(lds + 8192 + (wn * 64 + nt * 16 + lr) * 64 +
                                  (((ks * 4 + quad) ^ (lr & 7)) * 8));
#pragma unroll
      for (int mt = 0; mt < 4; ++mt)
#pragma unroll
        for (int nt = 0; nt < 4; ++nt)
          acc[mt][nt] = __builtin_amdgcn_mfma_f32_16x16x32_bf16(
              af[mt], bf[nt], acc[mt][nt], 0, 0, 0);
    }
    __syncthreads();
  }

  // ---- epilogue: C tile -> LDS -> coalesced global stores ----
  if (p == 2) {
#pragma unroll
    for (int nt = 0; nt < 4; ++nt) {
      const int nl = wn * 64 + nt * 16 + lr;
      const float bb = bias[n0 + nl];
#pragma unroll
      for (int mt = 0; mt < 4; ++mt) {
        union { short4v v; __hip_bfloat16 h4[4]; } u;
#pragma unroll
        for (int r = 0; r < 4; ++r) u.h4[r] = __float2bfloat16(acc[mt][nt][r] + bb);
        *(short4v*)(&lds[nl * CPAD + wm * 64 + mt * 16 + quad * 4]) = u.v;
      }
    }
  } else {
    const float scl = (p == 0) ? QSCALE : 1.0f;
#pragma unroll
    for (int nt = 0; nt < 4; ++nt) {
      const int nl = wn * 64 + nt * 16 + lr;
      const float bb = bias[n0 + nl];
#pragma unroll
      for (int mt = 0; mt < 4; ++mt)
#pragma unroll
        for (int r = 0; r < 4; ++r)
          lds[(wm * 64 + mt * 16 + quad * 4 + r) * CPAD + nl] =
              __float2bfloat16((acc[mt][nt][r] + bb) * scl);
    }
  }
  __syncthreads();

  {
    const int tr = tid >> 1, half = tid & 1;
    const int b = m0 >> 11;
    const __hip_bfloat16* src = lds + tr * CPAD + half * 64;
    __hip_bfloat16* g;
    if (p == 2) {
      const int ng = n0 + tr;
      const int h = ng >> 6, d = ng & 63;
      g = Vt + ((size_t)((b * NH + h) * DH + d)) * L_SEQ + (m0 & 2047) + half * 64;
    } else {
      __hip_bfloat16* dst = (p == 0) ? Qb : Kb;
      const int m = m0 + tr;
      const int h = (n0 >> 6) + half;
      g = dst + ((size_t)((b * NH + h) * L_SEQ + (m & 2047))) * DH;
    }
#pragma unroll
    for (int j = 0; j < 8; ++j)
      *(short8*)(g + j * 8) = *(const short8*)(src + j * 8);
  }
}

// ---------------- flash attention (S^T, max-free softmax, s-split, q=64/wave) ----
// grid = (8 q-tiles of 256, 32 bh, 2 s-halves). block = 256 (4 waves), q=64/wave.
// Each block handles 1024 keys (16 iters of 64, dbuf). Writes UNNORMALIZED bf16
// O-partials Op[sh][bh][l][d] (plain stores, no atomics) + psum partials psP.
// K/V LDS XOR-swizzled; P (64q x 64s per wave) swizzle with bit3-fold.
__global__ __launch_bounds__(256, 2) void attn_kernel(
    const __hip_bfloat16* __restrict__ Qb, const __hip_bfloat16* __restrict__ Kb,
    const __hip_bfloat16* __restrict__ Vt,
    __hip_bfloat16* __restrict__ Op0, __hip_bfloat16* __restrict__ Op1,
    float* __restrict__ psP) {
  __shared__ __align__(16) __hip_bfloat16 Kl[2][4096];   // [s][d] swizzled, 2 x 8 KB
  __shared__ __align__(16) __hip_bfloat16 Vl[2][4096];   // [d][s] swizzled, 2 x 8 KB
  __shared__ __align__(16) __hip_bfloat16 Pl[4][4096];   // per-wave P [q=64][s=64], 4 x 8 KB

  const int tid = threadIdx.x;
  const int w = tid >> 6, ln = tid & 63;
  const int quad = ln >> 4, lr = ln & 15;
  const int bh = blockIdx.y;
  const int sh = blockIdx.z;
  const int sbase = sh * 1024;
  const int q0 = blockIdx.x * 256 + w * 64;
  const __hip_bfloat16* Qp = Qb + (size_t)bh * L_SEQ * DH;
  const __hip_bfloat16* Kp = Kb + (size_t)bh * L_SEQ * DH;
  const __hip_bfloat16* Vp = Vt + (size_t)bh * DH * L_SEQ;
  __hip_bfloat16* Op = sh ? Op1 : Op0;

  // Q fragments as MFMA B-operand: B[n=q][k=d]; lane: n = lr, k = quad*8+j.
  short8 qf[4][2];
#pragma unroll
  for (int qs = 0; qs < 4; ++qs)
#pragma unroll
    for (int kk = 0; kk < 2; ++kk)
      qf[qs][kk] = *(const short8*)(Qp + (size_t)(q0 + qs * 16 + lr) * DH + kk * 32 + quad * 8);

  // staging: 512 16B-chunks per tile, 256 threads -> 2 chunks each per tile.
  int koff[2], voff[2], loff[2];
#pragma unroll
  for (int i = 0; i < 2; ++i) {
    const int idx = i * 256 + tid;
    const int srow = idx >> 3;
    const int c = (idx & 7) ^ (srow & 7);
    koff[i] = srow * DH + c * 8;      // K: [s][d]
    voff[i] = srow * L_SEQ + c * 8;   // V^T: [d][s]
    loff[i] = idx * 8;
  }

  floatx4 acc[4][4];  // [qs][nt], rows = q quad*4+r, col = d nt*16+lr
  float psum[4];
#pragma unroll
  for (int qs = 0; qs < 4; ++qs) {
    psum[qs] = 0.f;
#pragma unroll
    for (int nt = 0; nt < 4; ++nt) acc[qs][nt] = (floatx4){0.f, 0.f, 0.f, 0.f};
  }

  // prologue stage for iter 0
#pragma unroll
  for (int i = 0; i < 2; ++i) gl16(Kp + (size_t)sbase * DH + koff[i], &Kl[0][loff[i]]);
#pragma unroll
  for (int i = 0; i < 2; ++i) gl16(Vp + sbase + voff[i], &Vl[0][loff[i]]);

  const int xsw = lr & 7;                           // K/V swizzle (row&7 == lr&7)
  const int xswp = (lr & 7) ^ ((lr >> 3) << 2);     // P swizzle with bit3-fold

  for (int it = 0; it < 16; ++it) {
    __syncthreads();  // drains stage(it) issued one iteration ago
    if (it + 1 < 16) {
      const int s0 = sbase + (it + 1) * 64;
      const int bf = (it + 1) & 1;
#pragma unroll
      for (int i = 0; i < 2; ++i) gl16(Kp + (size_t)s0 * DH + koff[i], &Kl[bf][loff[i]]);
#pragma unroll
      for (int i = 0; i < 2; ++i) gl16(Vp + s0 + voff[i], &Vl[bf][loff[i]]);
    }
    const __hip_bfloat16* Kt = Kl[it & 1];
    const __hip_bfloat16* Vtile = Vl[it & 1];

    // S^T = K * Q^T, one 16-row s-subtile (mt) at a time; softmax + P write inline.
#pragma unroll
    for (int mt = 0; mt < 4; ++mt) {
      floatx4 sc[4];
#pragma unroll
      for (int qs = 0; qs < 4; ++qs) sc[qs] = (floatx4){0.f, 0.f, 0.f, 0.f};
#pragma unroll
      for (int kk = 0; kk < 2; ++kk) {
        const short8 kf = *(const short8*)(Kt + ((mt * 16 + lr) * 8 + ((kk * 4 + quad) ^ xsw)) * 8);
#pragma unroll
        for (int qs = 0; qs < 4; ++qs)
          sc[qs] = __builtin_amdgcn_mfma_f32_16x16x32_bf16(kf, qf[qs][kk], sc[qs], 0, 0, 0);
      }
      const int cch = mt * 2 + (quad >> 1);
#pragma unroll
      for (int qs = 0; qs < 4; ++qs) {
        union { short4v v; __hip_bfloat16 h4[4]; } u;
#pragma unroll
        for (int r = 0; r < 4; ++r) {
          const float pv = __builtin_amdgcn_exp2f(sc[qs][r]);
          psum[qs] += pv;
          u.h4[r] = __float2bfloat16(pv);
        }
        const int row = qs * 16 + lr;  // row bits 0-2 = lr&7; row bit 3 = lr>>3
        *(short4v*)(&Pl[w][row * 64 + ((cch ^ xswp) * 8 + (quad & 1) * 4)]) = u.v;
      }
    }

    // O += P V  (A = P [q][s], B = V^T [d][s])
#pragma unroll
    for (int kk = 0; kk < 2; ++kk) {
      short8 vf[4];
#pragma unroll
      for (int nt = 0; nt < 4; ++nt)
        vf[nt] = *(const short8*)(Vtile + ((nt * 16 + lr) * 8 + ((kk * 4 + quad) ^ xsw)) * 8);
#pragma unroll
      for (int qs = 0; qs < 4; ++qs) {
        const short8 pf = *(const short8*)(&Pl[w][(qs * 16 + lr) * 64 + ((kk * 4 + quad) ^ xswp) * 8]);
#pragma unroll
        for (int nt = 0; nt < 4; ++nt)
          acc[qs][nt] = __builtin_amdgcn_mfma_f32_16x16x32_bf16(pf, vf[nt], acc[qs][nt], 0, 0, 0);
      }
    }
  }

  // psum reduce across quads (each lane has its quad's s-slice for q = qs*16+lr)
#pragma unroll
  for (int qs = 0; qs < 4; ++qs) {
    psum[qs] += __shfl_xor(psum[qs], 16, 64);
    psum[qs] += __shfl_xor(psum[qs], 32, 64);
  }
  if (quad == 0) {
#pragma unroll
    for (int qs = 0; qs < 4; ++qs)
      psP[sh * (32 * L_SEQ) + bh * L_SEQ + q0 + qs * 16 + lr] = psum[qs];
  }

  // unnormalized bf16 O-partial store: Op[bh][l][d]
#pragma unroll
  for (int qs = 0; qs < 4; ++qs) {
#pragma unroll
    for (int r = 0; r < 4; ++r) {
      const int lq = q0 + qs * 16 + quad * 4 + r;
      __hip_bfloat16* dst = Op + ((size_t)(bh * L_SEQ + lq)) * DH;
#pragma unroll
      for (int nt = 0; nt < 4; ++nt)
        dst[nt * 16 + lr] = __float2bfloat16(acc[qs][nt][r]);
    }
  }
}

// ---------------- normalize: out = (Op0 + Op1) / (psum0 + psum1) ----------------
__global__ __launch_bounds__(256) void norm_kernel(float* __restrict__ out,
                                                   const __hip_bfloat16* __restrict__ Op0,
                                                   const __hip_bfloat16* __restrict__ Op1,
                                                   const float* __restrict__ psP) {
  const int idx4 = blockIdx.x * blockDim.x + threadIdx.x;  // one float4 of out each
  const int flat = idx4 * 4;
  const int e = flat & 1023;
  const int l = (flat >> 10) & 2047;
  const int b = flat >> 21;
  const int h = e >> 6, d = e & 63;
  const int bh = b * NH + h;
  const float ps = psP[bh * L_SEQ + l] + psP[32 * L_SEQ + bh * L_SEQ + l];
  const float inv = 1.0f / ps;
  const size_t src = ((size_t)(bh * L_SEQ + l)) * DH + d;
  union { short4v v; __hip_bfloat16 h4[4]; } a, c;
  a.v = *(const short4v*)(Op0 + src);
  c.v = *(const short4v*)(Op1 + src);
  float4 v;
  v.x = (__bfloat162float(a.h4[0]) + __bfloat162float(c.h4[0])) * inv;
  v.y = (__bfloat162float(a.h4[1]) + __bfloat162float(c.h4[1])) * inv;
  v.z = (__bfloat162float(a.h4[2]) + __bfloat162float(c.h4[2])) * inv;
  v.w = (__bfloat162float(a.h4[3]) + __bfloat162float(c.h4[3])) * inv;
  ((float4*)out)[idx4] = v;
}

extern "C" void kernel_launch(void* const* d_in, const int* in_sizes, int n_in,
                              void* d_out, int out_size, void* d_ws, size_t ws_size,
                              hipStream_t stream) {
  const float* xq = (const float*)d_in[0];
  const float* xk = (const float*)d_in[1];
  const float* xv = (const float*)d_in[2];
  const float* wq = (const float*)d_in[3];
  const float* bq = (const float*)d_in[4];
  const float* wk = (const float*)d_in[5];
  const float* bk = (const float*)d_in[6];
  const float* wv = (const float*)d_in[7];
  const float* bv = (const float*)d_in[8];

  const size_t NX = (size_t)4096 * 1024;  // x / q / k / v elements
  const size_t NW = (size_t)1024 * 1024;  // weight elements
  __hip_bfloat16* xbq = (__hip_bfloat16*)d_ws;
  __hip_bfloat16* xbk = xbq + NX;
  __hip_bfloat16* xbv = xbk + NX;
  __hip_bfloat16* wbq = xbv + NX;
  __hip_bfloat16* wbk = wbq + NW;
  __hip_bfloat16* wbv = wbk + NW;
  __hip_bfloat16* Qb = wbv + NW;
  __hip_bfloat16* Kb = Qb + NX;
  __hip_bfloat16* Vt = Kb + NX;
  // After proj, xbq/xbk/xbv/wbq are dead -> overlay attention partials there:
  __hip_bfloat16* Op0 = xbq;          // 8 MB bf16 [32][2048][64]
  __hip_bfloat16* Op1 = xbk;          // 8 MB
  float* psP = (float*)wbq;           // 512 KB [2][32][2048]
  // total ws use: 56.6 MB

  cvt6_kernel<<<dim3(1024, 6), 256, 0, stream>>>(xq, xk, xv, wq, wk, wv,
                                                 xbq, xbk, xbv, wbq, wbk, wbv,
                                                 (int)(NX / 8), (int)(NW / 8));

  proj_kernel<<<dim3(32, 24), 256, 0, stream>>>(xbq, xbk, xbv, wbq, wbk, wbv,
                                                bq, bk, bv, Qb, Kb, Vt);
  attn_kernel<<<dim3(8, 32, 2), 256, 0, stream>>>(Qb, Kb, Vt, Op0, Op1, psP);
  norm_kernel<<<4096, 256, 0, stream>>>((float*)d_out, Op0, Op1, psP);
}